// Round 1
// 273.846 us; speedup vs baseline: 1.1444x; 1.1444x over previous
//
#include <hip/hip_runtime.h>
#include <hip/hip_bf16.h>
#include <math.h>
#include <stdint.h>

#define N_NODES 50000
#define N_PAD   50048   // padded rows for MFMA tile overrun (row 50000 = zero/dummy row)
#define N_EDGES 800000
#define N_GRAPHS 256
#define F_IN 64
#define F_HID 128
#define N_HID 512
#define N_OUT 256
#define CSR_CAP (N_EDGES + 16 * N_NODES)  // align-16 padding headroom

#define NBKT   196           // buckets of 256 nodes (dst >> 8)
#define BKT_S  6144          // per-bucket capacity (expected 4096, +32 sigma)
#define EPB    3328          // edges per bin_edges block (13 * 256)
#define NBIN_BLK ((N_EDGES + EPB - 1) / EPB)   // 241
#define DUMMY_NODE N_NODES   // zero row index for CSR pad slots

using bf16x8 = __attribute__((ext_vector_type(8))) short;   // MFMA A/B frag (4 VGPRs)
using f32x4  = __attribute__((ext_vector_type(4))) float;   // MFMA C/D frag

// pack two fp32 into a uint holding two bf16 (RNE); low16 = a, high16 = b
__device__ __forceinline__ unsigned int bf16pair(float a, float b) {
    unsigned int ua = __float_as_uint(a);
    unsigned int ub = __float_as_uint(b);
    ua += 0x7fffu + ((ua >> 16) & 1u);
    ub += 0x7fffu + ((ub >> 16) & 1u);
    return (ua >> 16) | (ub & 0xffff0000u);
}
__device__ __forceinline__ float bf16lo(unsigned int u) { return __uint_as_float(u << 16); }
__device__ __forceinline__ float bf16hi(unsigned int u) { return __uint_as_float(u & 0xffff0000u); }

// accumulate 8 bf16 features from a uint4 into a[0..7]
__device__ __forceinline__ void acc8(float* a, uint4 r) {
    a[0] += bf16lo(r.x);  a[1] += bf16hi(r.x);
    a[2] += bf16lo(r.y);  a[3] += bf16hi(r.y);
    a[4] += bf16lo(r.z);  a[5] += bf16hi(r.z);
    a[6] += bf16lo(r.w);  a[7] += bf16hi(r.w);
}

// ---------------------------------------------------------------------------
// K0 (merged): xb'[s] = bf16(dis[s] * x[s]) + zero pad row; both weight tables
// fp32 [K][128] -> bf16 [128][K] in the same dispatch.
__global__ void cvt_all(const float* __restrict__ in, const float* __restrict__ dis,
                        unsigned int* __restrict__ xb,
                        const float* __restrict__ W0, unsigned short* __restrict__ W0Tb,
                        const float* __restrict__ W1, unsigned short* __restrict__ W1Tb) {
    const int NX = N_NODES * F_IN / 4;          // 800000 float4 slots
    int idx = blockIdx.x * blockDim.x + threadIdx.x;
    if (idx < NX) {
        int node = idx >> 4;                    // 16 float4 per 64-f row
        float d = dis[node];
        float4 v = ((const float4*)in)[idx];
        ((uint2*)xb)[idx] = make_uint2(bf16pair(d * v.x, d * v.y),
                                       bf16pair(d * v.z, d * v.w));
        if (idx < 16)                            // zero dummy row 50000
            ((uint2*)xb)[(size_t)N_NODES * 16 + idx] = make_uint2(0u, 0u);
    } else {
        int j = idx - NX;
        const int N0 = F_IN * 128;
        const int N1 = F_HID * 128;
        if (j < N0) {
            int k = j >> 7, n = j & 127;
            unsigned int u = __float_as_uint(W0[j]);
            u += 0x7fffu + ((u >> 16) & 1u);
            W0Tb[n * F_IN + k] = (unsigned short)(u >> 16);
        } else if (j < N0 + N1) {
            int jj = j - N0;
            int k = jj >> 7, n = jj & 127;
            unsigned int u = __float_as_uint(W1[jj]);
            u += 0x7fffu + ((u >> 16) & 1u);
            W1Tb[n * F_HID + k] = (unsigned short)(u >> 16);
        }
    }
}

// ---------------------------------------------------------------------------
// K1: bin edges by dst>>8 through LDS staging (privatized binning).
// Packed entry: (bucket<<24) | (src<<8) | (dst & 255) — bucket stripped on
// copy-out. One global atomicAdd per (block,bucket); bulk copy-out coalesced.
__global__ __launch_bounds__(256) void bin_edges(const int* __restrict__ ei,
                                                 int* __restrict__ bucketCur,
                                                 unsigned int* __restrict__ binned) {
    __shared__ int hist[NBKT];
    __shared__ int lbase[NBKT];
    __shared__ int lcur[NBKT];
    __shared__ int gbase[NBKT];
    __shared__ int scn[256];
    __shared__ unsigned int staging[EPB];
    int tid = threadIdx.x;
    int base = blockIdx.x * EPB;
    int cnt = N_EDGES - base; if (cnt > EPB) cnt = EPB;
    if (tid < NBKT) hist[tid] = 0;
    __syncthreads();
    unsigned int pk[13]; int nk = 0;
#pragma unroll
    for (int u = 0; u < 13; ++u) {
        int e = base + u * 256 + tid;
        if (u * 256 + tid < cnt) {
            unsigned int s = (unsigned int)ei[e];
            unsigned int d = (unsigned int)ei[N_EDGES + e];
            unsigned int b = d >> 8;
            pk[nk++] = (b << 24) | (s << 8) | (d & 255u);
        }
    }
    for (int u = 0; u < nk; ++u) atomicAdd(&hist[pk[u] >> 24], 1);
    __syncthreads();
    // parallel exclusive scan over the 196 bucket counts
    int h = (tid < NBKT) ? hist[tid] : 0;
    scn[tid] = h;
    __syncthreads();
    for (int off = 1; off < 256; off <<= 1) {
        int t = (tid >= off) ? scn[tid - off] : 0;
        __syncthreads();
        scn[tid] += t;
        __syncthreads();
    }
    if (tid < NBKT) { int e0 = scn[tid] - h; lbase[tid] = e0; lcur[tid] = e0; }
    __syncthreads();
    for (int u = 0; u < nk; ++u) {
        int pos = atomicAdd(&lcur[pk[u] >> 24], 1);
        staging[pos] = pk[u];
    }
    if (tid < NBKT && hist[tid] > 0)
        gbase[tid] = atomicAdd(&bucketCur[tid], hist[tid]);
    __syncthreads();
    for (int k = tid; k < cnt; k += 256) {
        unsigned int v = staging[k];
        int b = v >> 24;
        binned[(size_t)b * BKT_S + gbase[b] + (k - lbase[b])] = v & 0xffffffu;
    }
}

// K2a: per-bucket degree histogram -> degs, dis, align-16 local offsets.
// 256-node buckets: one node per thread, parallel scan.
__global__ __launch_bounds__(256) void bucket_deg(const unsigned int* __restrict__ binned,
                                                  const int* __restrict__ bucketCur,
                                                  int* __restrict__ degs,
                                                  float* __restrict__ dis,
                                                  int* __restrict__ localOff,
                                                  int* __restrict__ bucketAligned) {
    __shared__ int hist[256];
    __shared__ int tsum[256];
    int b = blockIdx.x;
    int tid = threadIdx.x;
    int node0 = b << 8;
    hist[tid] = 0;
    __syncthreads();
    int cnt = bucketCur[b];
    const unsigned int* bb = &binned[(size_t)b * BKT_S];
    for (int k = tid; k < cnt; k += 256)
        atomicAdd(&hist[bb[k] & 255u], 1);
    __syncthreads();
    int d = hist[tid];
    int s = (d + 15) & ~15;          // align-16 so aggregates run full 16-edge chunks
    tsum[tid] = s;
    __syncthreads();
    for (int off = 1; off < 256; off <<= 1) {
        int t = (tid >= off) ? tsum[tid - off] : 0;
        __syncthreads();
        tsum[tid] += t;
        __syncthreads();
    }
    int excl = tsum[tid] - s;
    int node = node0 + tid;
    if (node < N_NODES) {
        degs[node] = d;
        dis[node] = rsqrtf((float)(d + 1));
        localOff[node] = excl;
    }
    if (tid == 255) bucketAligned[b] = tsum[255];
}

// K2b: per-bucket CSR scatter. csrBase computed in-block (redundant 196-int
// scan, removes the csr_base_scan dispatch). Pad slots pre-filled with
// DUMMY_NODE so aggregates need no masked tail.
__global__ __launch_bounds__(256) void scatter_local(const unsigned int* __restrict__ binned,
                                                     const int* __restrict__ bucketCur,
                                                     const int* __restrict__ bucketAligned,
                                                     const int* __restrict__ localOff,
                                                     int* __restrict__ offsets,
                                                     unsigned short* __restrict__ csr) {
    __shared__ int lcur[256];
    __shared__ int sc[256];
    __shared__ int s_csrB, s_tot;
    int b = blockIdx.x;
    int tid = threadIdx.x;
    sc[tid] = (tid < NBKT) ? bucketAligned[tid] : 0;
    __syncthreads();
    for (int off = 1; off < 256; off <<= 1) {
        int t = (tid >= off) ? sc[tid - off] : 0;
        __syncthreads();
        sc[tid] += t;
        __syncthreads();
    }
    if (tid == 0) {
        int incl = sc[b];
        int mine = bucketAligned[b];
        s_csrB = incl - mine;
        s_tot  = mine;
    }
    __syncthreads();
    int csrB = s_csrB;
    int tot  = s_tot;
    int node = (b << 8) + tid;
    int lo = (node < N_NODES) ? localOff[node] : 0;
    lcur[tid] = lo;
    if (node < N_NODES) offsets[node] = csrB + lo;
    // dummy-fill the whole aligned region (uint4 = 8 entries; tot % 16 == 0)
    uint4 dv = make_uint4(0xC350C350u, 0xC350C350u, 0xC350C350u, 0xC350C350u); // 50000|50000<<16
    uint4* cp = (uint4*)(csr + csrB);
    for (int k = tid; k < (tot >> 3); k += 256) cp[k] = dv;
    __syncthreads();
    int cnt = bucketCur[b];
    const unsigned int* bb = &binned[(size_t)b * BKT_S];
    for (int k = tid; k < cnt; k += 256) {
        unsigned int v = bb[k];
        int dl = v & 255u;
        int p = atomicAdd(&lcur[dl], 1);
        csr[csrB + p] = (unsigned short)(v >> 8);
    }
}

// ---------------------------------------------------------------------------
// K4: MFMA GEMM. C[M,128] = A[M,K]@W[K,128], A bf16 [M][K], WT bf16 [128][K].
// Rows in [M, N_PAD) are stored as zeros (dummy row for gathers).
template <int K, bool BIASRELU, bool DISSCALE>
__global__ __launch_bounds__(256) void gemm_mfma(const unsigned short* __restrict__ Ab,
                                                 const unsigned short* __restrict__ WTb,
                                                 const float* __restrict__ bias,
                                                 const float* __restrict__ disv,
                                                 unsigned int* __restrict__ outb, int M) {
    int wv = threadIdx.x >> 6;
    int lane = threadIdx.x & 63;
    int m = lane & 15;
    int quad = lane >> 4;
    int row0 = blockIdx.x * 64 + wv * 16;
    f32x4 acc[8];
#pragma unroll
    for (int t = 0; t < 8; ++t) acc[t] = (f32x4){0.f, 0.f, 0.f, 0.f};
#pragma unroll
    for (int ks = 0; ks < K; ks += 32) {
        bf16x8 af = *(const bf16x8*)&Ab[(size_t)(row0 + m) * K + ks + quad * 8];
#pragma unroll
        for (int t = 0; t < 8; ++t) {
            bf16x8 bf = *(const bf16x8*)&WTb[(size_t)(t * 16 + m) * K + ks + quad * 8];
            acc[t] = __builtin_amdgcn_mfma_f32_16x16x32_bf16(af, bf, acc[t], 0, 0, 0);
        }
    }
    float dr[4];
#pragma unroll
    for (int r = 0; r < 4; ++r) {
        int row = row0 + quad * 4 + r;
        dr[r] = DISSCALE ? ((row < M) ? disv[row] : 0.f) : 1.f;
    }
#pragma unroll
    for (int t = 0; t < 8; ++t) {
        int col = t * 16 + m;
        float bcol = 0.f;
        if (BIASRELU) bcol = bias[col];
#pragma unroll
        for (int r = 0; r < 4; ++r) {
            float v = acc[t][r];
            if (BIASRELU) v = fmaxf(v + bcol, 0.f);
            if (DISSCALE) v = v * dr[r];
            float vn = __shfl_xor(v, 1, 64);    // neighbor col's value
            if ((m & 1) == 0) {
                int row = row0 + quad * 4 + r;
                if (row < M)
                    outb[(size_t)row * 64 + (col >> 1)] = bf16pair(v, vn);
                else
                    outb[(size_t)row * 64 + (col >> 1)] = 0u;   // zero pad row
            }
        }
    }
}

// ---------------------------------------------------------------------------
// K5a: F=128 aggregate over PRE-SCALED bf16 table. uint4 lanes (4 edges/inst),
// dummy-padded CSR -> all chunks full, no tail. Extra block writes zero row.
template <bool RELU, bool BIAS, bool SCALEOUT>
__global__ __launch_bounds__(256) void aggregate128b(const uint4* __restrict__ hb4,
                                                     const int* __restrict__ offsets,
                                                     const int* __restrict__ degs,
                                                     const unsigned short* __restrict__ csr,
                                                     const float* __restrict__ dis,
                                                     const float* __restrict__ bias,
                                                     unsigned int* __restrict__ outb) {
    int wave = threadIdx.x >> 6;
    int lane = threadIdx.x & 63;
    int i = blockIdx.x * 4 + wave;
    int sub = lane >> 4;              // 0..3: which edge-quad
    int q   = lane & 15;              // uint4 index within the 16-uint4 row
    if (i >= N_NODES) {
        if (i == N_NODES && sub == 0)  // zero dummy row for downstream gathers
            ((uint4*)outb)[(size_t)N_NODES * 16 + q] = make_uint4(0u, 0u, 0u, 0u);
        return;
    }
    float a[8];
#pragma unroll
    for (int k = 0; k < 8; ++k) a[k] = 0.f;
    int j = offsets[i];
    int e1 = j + ((degs[i] + 15) & ~15);
    for (; j < e1; j += 16) {
        uint2 w = *(const uint2*)&csr[j + 4 * sub];
        int s0 = w.x & 0xffff, s1 = w.x >> 16;
        int s2 = w.y & 0xffff, s3 = w.y >> 16;
        uint4 r0 = hb4[(size_t)s0 * 16 + q];
        uint4 r1 = hb4[(size_t)s1 * 16 + q];
        uint4 r2 = hb4[(size_t)s2 * 16 + q];
        uint4 r3 = hb4[(size_t)s3 * 16 + q];
        acc8(a, r0); acc8(a, r1); acc8(a, r2); acc8(a, r3);
    }
#pragma unroll
    for (int k = 0; k < 8; ++k) a[k] += __shfl_xor(a[k], 16, 64);
#pragma unroll
    for (int k = 0; k < 8; ++k) a[k] += __shfl_xor(a[k], 32, 64);
    uint4 su = hb4[(size_t)i * 16 + q];     // self: weight 1 in scaled domain
    acc8(a, su);
    float dii = dis[i];
#pragma unroll
    for (int k = 0; k < 8; ++k) a[k] *= dii;
    if (BIAS) {
        float4 b0 = ((const float4*)bias)[2 * q];
        float4 b1 = ((const float4*)bias)[2 * q + 1];
        a[0] += b0.x; a[1] += b0.y; a[2] += b0.z; a[3] += b0.w;
        a[4] += b1.x; a[5] += b1.y; a[6] += b1.z; a[7] += b1.w;
    }
    if (RELU) {
#pragma unroll
        for (int k = 0; k < 8; ++k) a[k] = fmaxf(a[k], 0.f);
    }
    if (sub == 0) {
        float sc = SCALEOUT ? dii : 1.f;
        ((uint4*)outb)[(size_t)i * 16 + q] =
            make_uint4(bf16pair(sc * a[0], sc * a[1]), bf16pair(sc * a[2], sc * a[3]),
                       bf16pair(sc * a[4], sc * a[5]), bf16pair(sc * a[6], sc * a[7]));
    }
}

// K5b: F=64 aggregate over pre-scaled bf16 x-table. uint4 lanes, 8 edges/inst.
__global__ __launch_bounds__(256) void aggregate_xb(const uint4* __restrict__ xb4,
                                                    const float* __restrict__ x,
                                                    const int* __restrict__ offsets,
                                                    const int* __restrict__ degs,
                                                    const unsigned short* __restrict__ csr,
                                                    const float* __restrict__ dis,
                                                    unsigned int* __restrict__ outb) {
    int wave = threadIdx.x >> 6;
    int lane = threadIdx.x & 63;
    int i = blockIdx.x * 4 + wave;
    int sub = lane >> 3;              // 0..7: which edge-pair
    int q   = lane & 7;               // uint4 index within the 8-uint4 row
    if (i >= N_NODES) {
        if (i == N_NODES && sub == 0)
            ((uint4*)outb)[(size_t)N_NODES * 8 + q] = make_uint4(0u, 0u, 0u, 0u);
        return;
    }
    float a[8];
#pragma unroll
    for (int k = 0; k < 8; ++k) a[k] = 0.f;
    int j = offsets[i];
    int e1 = j + ((degs[i] + 15) & ~15);
    for (; j < e1; j += 16) {
        unsigned int w = *(const unsigned int*)&csr[j + 2 * sub];
        int s0 = w & 0xffff, s1 = w >> 16;
        uint4 r0 = xb4[(size_t)s0 * 8 + q];
        uint4 r1 = xb4[(size_t)s1 * 8 + q];
        acc8(a, r0); acc8(a, r1);
    }
#pragma unroll
    for (int k = 0; k < 8; ++k) a[k] += __shfl_xor(a[k], 8, 64);
#pragma unroll
    for (int k = 0; k < 8; ++k) a[k] += __shfl_xor(a[k], 16, 64);
#pragma unroll
    for (int k = 0; k < 8; ++k) a[k] += __shfl_xor(a[k], 32, 64);
    float dii = dis[i];
    float d2 = dii * dii;
    float4 sx0 = ((const float4*)x)[(size_t)i * 16 + 2 * q];       // self in fp32
    float4 sx1 = ((const float4*)x)[(size_t)i * 16 + 2 * q + 1];
    a[0] = dii * a[0] + d2 * sx0.x;  a[1] = dii * a[1] + d2 * sx0.y;
    a[2] = dii * a[2] + d2 * sx0.z;  a[3] = dii * a[3] + d2 * sx0.w;
    a[4] = dii * a[4] + d2 * sx1.x;  a[5] = dii * a[5] + d2 * sx1.y;
    a[6] = dii * a[6] + d2 * sx1.z;  a[7] = dii * a[7] + d2 * sx1.w;
    if (sub == 0)
        ((uint4*)outb)[(size_t)i * 8 + q] =
            make_uint4(bf16pair(a[0], a[1]), bf16pair(a[2], a[3]),
                       bf16pair(a[4], a[5]), bf16pair(a[6], a[7]));
}

// ---------------------------------------------------------------------------
// K6: mean-pool over bf16 table (batch sorted -> register-accumulate, flush on change)
__global__ __launch_bounds__(128) void pool16(const unsigned int* __restrict__ hb,
                                              const int* __restrict__ batch,
                                              float* __restrict__ g_acc,
                                              float* __restrict__ g_cnt) {
    const int NB = 16;
    int base = blockIdx.x * NB;
    int f = threadIdx.x;              // feature 0..127
    int uidx = f >> 1;                // uint index within 64-uint row
    bool hi = f & 1;
    float acc = 0.f;
    int cur = -1, cnt = 0;
    for (int n = 0; n < NB; ++n) {
        int i = base + n;
        if (i >= N_NODES) break;
        int b = batch[i];
        if (b != cur) {
            if (cur >= 0) {
                atomicAdd(&g_acc[(size_t)cur * F_HID + f], acc);
                if (f == 0) atomicAdd(&g_cnt[cur], (float)cnt);
            }
            cur = b; acc = 0.f; cnt = 0;
        }
        unsigned int u = hb[(size_t)i * 64 + uidx];
        acc += hi ? bf16hi(u) : bf16lo(u);
        cnt++;
    }
    if (cur >= 0) {
        atomicAdd(&g_acc[(size_t)cur * F_HID + f], acc);
        if (f == 0) atomicAdd(&g_cnt[cur], (float)cnt);
    }
}

// ---------------------------------------------------------------------------
// K7: fused graph head: g2 = (g_acc/cnt)@W2 + b2; g_hid = relu(g2@Wm1+bm1);
// out = g_hid@Wm2 + bm2.  One block per graph, 512 threads.
__global__ __launch_bounds__(512) void fused_mlp(const float* __restrict__ g_acc,
                                                 const float* __restrict__ g_cnt,
                                                 const float* __restrict__ W2,
                                                 const float* __restrict__ b2,
                                                 const float* __restrict__ Wm1,
                                                 const float* __restrict__ bm1,
                                                 const float* __restrict__ Wm2,
                                                 const float* __restrict__ bm2,
                                                 float* __restrict__ out) {
    __shared__ float pool_row[F_HID];
    __shared__ float g2row[F_HID];
    __shared__ float hid[N_HID];
    int g = blockIdx.x;
    int t = threadIdx.x;              // 0..511
    if (t < F_HID) {
        float c = g_cnt[g];
        pool_row[t] = g_acc[(size_t)g * F_HID + t] / fmaxf(c, 1.0f);
    }
    __syncthreads();
    if (t < F_HID) {
        float acc = b2[t];
        for (int k = 0; k < F_HID; ++k) acc += pool_row[k] * W2[(size_t)k * F_HID + t];
        g2row[t] = acc;
    }
    __syncthreads();
    {
        float acc = bm1[t];
        for (int k = 0; k < F_HID; ++k) acc += g2row[k] * Wm1[(size_t)k * N_HID + t];
        hid[t] = fmaxf(acc, 0.f);
    }
    __syncthreads();
    if (t < N_OUT) {
        float acc = bm2[t];
        for (int k = 0; k < N_HID; ++k) acc += hid[k] * Wm2[(size_t)k * N_OUT + t];
        out[(size_t)g * N_OUT + t] = acc;
    }
}

// ---------------------------------------------------------------------------
extern "C" void kernel_launch(void* const* d_in, const int* in_sizes, int n_in,
                              void* d_out, int out_size, void* d_ws, size_t ws_size,
                              hipStream_t stream) {
    const float* x   = (const float*)d_in[0];
    const int* ei    = (const int*)d_in[1];     // [2, E] int32
    const int* batch = (const int*)d_in[2];
    const float* W0 = (const float*)d_in[3];  const float* b0 = (const float*)d_in[4];
    const float* W1 = (const float*)d_in[5];  const float* b1 = (const float*)d_in[6];
    const float* W2 = (const float*)d_in[7];  const float* b2 = (const float*)d_in[8];
    const float* Wm1 = (const float*)d_in[9];  const float* bm1 = (const float*)d_in[10];
    const float* Wm2 = (const float*)d_in[11]; const float* bm2 = (const float*)d_in[12];

    // bump allocator on d_ws, 256B-aligned slots
    char* p = (char*)d_ws;
    auto alloc = [&](size_t bytes) -> char* {
        char* r = p;
        p += (bytes + 255) & ~(size_t)255;
        return r;
    };
    // zero-init region (contiguous in allocation order)
    int*   bucketCur = (int*)alloc(NBKT * 4);
    float* g_acc  = (float*)alloc((size_t)N_GRAPHS * F_HID * 4);
    float* g_cnt  = (float*)alloc(N_GRAPHS * 4);
    size_t zero_bytes = (size_t)(p - (char*)bucketCur);
    // rest
    unsigned int* binned = (unsigned int*)alloc((size_t)NBKT * BKT_S * 4);
    int*   bucketAligned = (int*)alloc(NBKT * 4);
    int*   offsets = (int*)alloc((size_t)N_NODES * 4);
    int*   degs    = (int*)alloc((size_t)N_NODES * 4);
    int*   localOff = (int*)alloc((size_t)N_NODES * 4);
    float* dis     = (float*)alloc((size_t)N_NODES * 4);
    unsigned short* csr = (unsigned short*)alloc((size_t)CSR_CAP * 2 + 32);
    unsigned int* xb     = (unsigned int*)alloc((size_t)N_PAD * F_IN / 2 * 4);   // bf16 x' (dis-scaled) + zero row
    unsigned int* axb    = (unsigned int*)alloc((size_t)N_PAD * F_IN / 2 * 4);   // bf16 Âx (plain)
    unsigned int* h_ab   = (unsigned int*)alloc((size_t)N_PAD * F_HID / 2 * 4);  // bf16 h_a (plain)
    unsigned int* h_tmpb = (unsigned int*)alloc((size_t)N_PAD * F_HID / 2 * 4);  // bf16 (dis-scaled) + zero pad
    unsigned int* h_bb   = (unsigned int*)alloc((size_t)N_PAD * F_HID / 2 * 4);  // bf16 (dis-scaled) + zero row
    unsigned int* agg2b  = (unsigned int*)alloc((size_t)N_PAD * F_HID / 2 * 4);  // bf16 (plain)
    unsigned short* W0Tb = (unsigned short*)alloc((size_t)128 * F_IN * 2);
    unsigned short* W1Tb = (unsigned short*)alloc((size_t)128 * F_HID * 2);
    (void)ws_size; (void)in_sizes; (void)n_in; (void)out_size;

    (void)hipMemsetAsync(bucketCur, 0, zero_bytes, stream);

    // CSR construction: privatized binning -> per-bucket local CSR (196 buckets)
    bin_edges<<<NBIN_BLK, 256, 0, stream>>>(ei, bucketCur, binned);
    bucket_deg<<<NBKT, 256, 0, stream>>>(binned, bucketCur, degs, dis, localOff, bucketAligned);

    const int NCVT = N_NODES * F_IN / 4 + (F_IN + F_HID) * 128;
    cvt_all<<<(NCVT + 255) / 256, 256, 0, stream>>>(x, dis, xb, W0, W0Tb, W1, W1Tb);

    scatter_local<<<NBKT, 256, 0, stream>>>(binned, bucketCur, bucketAligned, localOff,
                                            offsets, csr);

    int agg_grid = N_NODES / 4 + 1;            // 12501: last block writes zero rows
    int mfma_grid = N_PAD / 64;                // 782 blocks

    // layer 0 (reordered): axb = bf16(Â x); h_ab = bf16(relu(axb @ W0 + b0))
    aggregate_xb<<<agg_grid, 256, 0, stream>>>((const uint4*)xb, x, offsets, degs, csr, dis, axb);
    gemm_mfma<F_IN, true, false><<<mfma_grid, 256, 0, stream>>>(
        (const unsigned short*)axb, W0Tb, b0, nullptr, h_ab, N_NODES);
    // layer 1: h_tmpb = bf16(dis * (h_ab @ W1)); h_bb = bf16(dis * relu(Â.. + b1))
    gemm_mfma<F_HID, false, true><<<mfma_grid, 256, 0, stream>>>(
        (const unsigned short*)h_ab, W1Tb, nullptr, dis, h_tmpb, N_NODES);
    aggregate128b<true, true, true><<<agg_grid, 256, 0, stream>>>(
        (const uint4*)h_tmpb, offsets, degs, csr, dis, b1, h_bb);
    // layer 2 (commuted): agg2b = bf16(Â h_bb); pool; then @W2 + b2 in fused head
    aggregate128b<false, false, false><<<agg_grid, 256, 0, stream>>>(
        (const uint4*)h_bb, offsets, degs, csr, dis, nullptr, agg2b);

    // pool + fused (W2 + MLP) head
    pool16<<<(N_NODES + 15) / 16, 128, 0, stream>>>(agg2b, batch, g_acc, g_cnt);
    fused_mlp<<<N_GRAPHS, 512, 0, stream>>>(g_acc, g_cnt, W2, b2, Wm1, bm1, Wm2, bm2,
                                            (float*)d_out);
}